// Round 2
// baseline (267.761 us; speedup 1.0000x reference)
//
#include <hip/hip_runtime.h>
#include <hip/hip_bf16.h>
#include <stdint.h>
#include <math.h>

#define BB 32768
#define FEAT 512
#define SPD_H 128
#define CTRL_H 256
#define NCMD 4

typedef __attribute__((ext_vector_type(8))) short bf16x8;
typedef __attribute__((ext_vector_type(4))) float f32x4;

__device__ __forceinline__ unsigned short f2bf(float f) {
  union { float f; uint32_t u; } v; v.f = f;
  uint32_t u = v.u;
  return (unsigned short)((u + 0x7fffu + ((u >> 16) & 1u)) >> 16); // RNE
}

__device__ __forceinline__ bf16x8 pack8(float4 a, float4 b) {
  bf16x8 r;
  r[0] = (short)f2bf(a.x); r[1] = (short)f2bf(a.y);
  r[2] = (short)f2bf(a.z); r[3] = (short)f2bf(a.w);
  r[4] = (short)f2bf(b.x); r[5] = (short)f2bf(b.y);
  r[6] = (short)f2bf(b.z); r[7] = (short)f2bf(b.w);
  return r;
}

// async global->LDS, 16B per lane; LDS dest = wave-uniform base + lane*16
__device__ __forceinline__ void async16(const unsigned short* g, unsigned short* l) {
  __builtin_amdgcn_global_load_lds(
      (const __attribute__((address_space(1))) unsigned int*)g,
      (__attribute__((address_space(3))) unsigned int*)l, 16, 0, 0);
}

// ---------------- shared 128x128 bf16 MFMA GEMM tile (device fn) --------------
// Used only by k_mid's W_f fuse GEMM now. 16 KB of DYNAMIC LDS.
__device__ __forceinline__ void gemm128(
    const unsigned short* __restrict__ A, int lda,
    const int* __restrict__ perm, int m_start, int m_cnt,
    const unsigned short* __restrict__ W, const float* __restrict__ bi,
    unsigned short* __restrict__ C, int ldc, int relu, int K, int mt, int nt) {
  extern __shared__ __align__(16) unsigned char dynsm[];
  unsigned short* As = (unsigned short*)dynsm;
  unsigned short* Bs = As + 128 * 32;

  const int m0 = mt * 128;
  if (m0 >= m_cnt) return;
  const int n0 = nt * 128;
  const int t = threadIdx.x;
  const int w = t >> 6, lane = t & 63;
  const int wm = w & 1, wn = w >> 1;

  f32x4 acc[4][4];
#pragma unroll
  for (int i = 0; i < 4; ++i)
#pragma unroll
    for (int j = 0; j < 4; ++j)
#pragma unroll
      for (int r = 0; r < 4; ++r) acc[i][j][r] = 0.f;

  const int fr = lane & 15;
  const int fk = (lane >> 4) * 8;

  const unsigned short* agp[2]; const unsigned short* bgp[2];
  unsigned short* al[2]; unsigned short* bl[2];
#pragma unroll
  for (int it = 0; it < 2; ++it) {
    int row = w * 32 + it * 16 + (lane >> 2);
    int seg8 = (lane & 3) * 8;
    int rl = m0 + row;
    if (rl >= m_cnt) rl = m_cnt - 1;
    int grow = perm ? perm[m_start + rl] : (m_start + rl);
    agp[it] = A + (size_t)grow * lda + seg8;
    bgp[it] = W + (size_t)(n0 + row) * K + seg8;
    al[it] = As + (w * 32 + it * 16) * 32;
    bl[it] = Bs + (w * 32 + it * 16) * 32;
  }

  for (int k0 = 0; k0 < K; k0 += 32) {
#pragma unroll
    for (int it = 0; it < 2; ++it) {
      async16(agp[it] + k0, al[it]);
      async16(bgp[it] + k0, bl[it]);
    }
    __syncthreads();
    bf16x8 af[4], bfv[4];
#pragma unroll
    for (int i = 0; i < 4; ++i)
      af[i] = *(const bf16x8*)(As + (wm * 64 + i * 16 + fr) * 32 + fk);
#pragma unroll
    for (int j = 0; j < 4; ++j)
      bfv[j] = *(const bf16x8*)(Bs + (wn * 64 + j * 16 + fr) * 32 + fk);
#pragma unroll
    for (int i = 0; i < 4; ++i)
#pragma unroll
      for (int j = 0; j < 4; ++j)
        acc[i][j] = __builtin_amdgcn_mfma_f32_16x16x32_bf16(af[i], bfv[j], acc[i][j], 0, 0, 0);
    __syncthreads();
  }

  const int rquad = (lane >> 4) * 4;
  const int cidx = lane & 15;

  float bv[4];
#pragma unroll
  for (int j = 0; j < 4; ++j) bv[j] = bi ? bi[n0 + wn * 64 + j * 16 + cidx] : 0.f;

  unsigned short (*bscr)[136] = (unsigned short(*)[136])dynsm;
#pragma unroll
  for (int c = 0; c < 4; ++c) {
    if (wm == (c >> 1)) {
#pragma unroll
      for (int j = 0; j < 4; ++j) {
#pragma unroll
        for (int ii = 0; ii < 2; ++ii) {
          int i = 2 * (c & 1) + ii;
          int lr = ii * 16 + rquad;
#pragma unroll
          for (int r = 0; r < 4; ++r) {
            float v = acc[i][j][r] + bv[j];
            if (relu) v = fmaxf(v, 0.f);
            bscr[lr + r][wn * 64 + j * 16 + cidx] = f2bf(v);
          }
        }
      }
    }
    __syncthreads();
#pragma unroll
    for (int q = 0; q < 2; ++q) {
      int sg = t + 256 * q;
      int lr = sg >> 4, cs = (sg & 15) * 8;
      int grow = m0 + c * 32 + lr;
      if (grow < m_cnt)
        *(bf16x8*)(C + (size_t)(m_start + grow) * ldc + (n0 + cs)) =
            *(const bf16x8*)(&bscr[lr][cs]);
    }
    __syncthreads();
  }
}

// --- prep: weight converts/transposes + count + b_f (feat pass REMOVED -------
// k_tail now reads feat f32 directly and converts in-register; ajoin is gone).
struct WSeg { const float* src; unsigned short* dst; int K; int N; int ldd; };
struct PrepArgs {
  WSeg s[12];
  int start[13];
  const float* join_w; unsigned short* wjbf;
  const int* cmd; int* wavecnt;
  const float* join_b; const float* ctrl_w1; const float* ctrl_b1; float* b_f;
};
__launch_bounds__(256)
__global__ void k_prep(PrepArgs a) {
  int bx = blockIdx.x, t = threadIdx.x;
  if (bx < 320) {            // ---- join_w straight convert
    int idx = bx * 256 + t;
    float4 f = *(const float4*)(a.join_w + (size_t)idx * 4);
    ushort4 o;
    o.x = f2bf(f.x); o.y = f2bf(f.y); o.z = f2bf(f.z); o.w = f2bf(f.w);
    *(ushort4*)(a.wjbf + (size_t)idx * 4) = o;
    return;
  }
  int rel = bx - 320;
  if (rel < a.start[12]) {   // ---- 32x32 transpose tiles
    __shared__ float tb[32][33];
    int si = 0;
    while (rel >= a.start[si + 1]) ++si;
    WSeg sg = a.s[si];
    int tile = rel - a.start[si];
    int tkx = sg.K >> 5;
    int tn = tile / tkx;
    int tk = tile - tn * tkx;
    int k0 = tk * 32, n0 = tn * 32;
    int tx = t & 31, ty = t >> 5;
#pragma unroll
    for (int j = 0; j < 4; ++j)
      tb[ty + j * 8][tx] = sg.src[(size_t)(k0 + ty + j * 8) * sg.N + n0 + tx];
    __syncthreads();
#pragma unroll
    for (int j = 0; j < 4; ++j)
      sg.dst[(size_t)(n0 + ty + j * 8) * sg.ldd + k0 + tx] = f2bf(tb[tx][ty + j * 8]);
    return;
  }
  rel -= a.start[12];
  if (rel < 128) {           // ---- command count (ballot histogram)
    int i = rel * 256 + t;
    int c = a.cmd[i];
    int wid = i >> 6;
    int lane = t & 63;
#pragma unroll
    for (int cv = 0; cv < NCMD; ++cv) {
      unsigned long long m = __ballot(c == cv);
      if (lane == 0) a.wavecnt[cv * 512 + wid] = __popcll(m);
    }
    return;
  }
  // ---- b_f[e][n] = join_b . ctrl_w1[e][:,n] + ctrl_b1[e][n]
  int e = rel - 128;
  float s0 = a.ctrl_b1[e * 256 + t], s1 = 0.f, s2 = 0.f, s3 = 0.f;
  const float* w = a.ctrl_w1 + (size_t)e * 512 * 256 + t;
#pragma unroll 4
  for (int m = 0; m < 512; m += 4) {
    s0 = fmaf(a.join_b[m + 0], w[(size_t)(m + 0) * 256], s0);
    s1 = fmaf(a.join_b[m + 1], w[(size_t)(m + 1) * 256], s1);
    s2 = fmaf(a.join_b[m + 2], w[(size_t)(m + 2) * 256], s2);
    s3 = fmaf(a.join_b[m + 3], w[(size_t)(m + 3) * 256], s3);
  }
  a.b_f[e * 256 + t] = (s0 + s1) + (s2 + s3);
}

// -- k_mid: place (0..127) + W_f fuse GEMM (128..167) + ms module (168..423) ---
// ms output now goes to compact msout[B][128] (contiguous) instead of ajoin.
struct MidArgs {
  const int* cmd; const int* wavecnt; int* perm; int* offs;
  const unsigned short* c_w1t; const unsigned short* wjbf; unsigned short* wf_t;
  const float* speed;
  const float* ms_w1; const float* ms_b1;
  const unsigned short* ms_w2t; const float* ms_b2;
  const unsigned short* ms_w3t; const float* ms_b3;
  unsigned short* msout;
  int* tile_e; int* tile_r0; int* ntl;
};
__launch_bounds__(256)
__global__ void k_mid(MidArgs a) {
  int b = blockIdx.x, t = threadIdx.x;
  if (b >= 168) {            // ---- measured-speed module (MFMA, LDS-resident)
    extern __shared__ __align__(16) unsigned char dynsm[];
    unsigned short (*hw)[136] = (unsigned short(*)[136])dynsm;
    unsigned short* BsM = (unsigned short*)(dynsm + 128 * 136 * 2);
    const int m0 = (b - 168) * 128;
    const int w = t >> 6, lane = t & 63;
    const int wm = w & 1, wn = w >> 1;
    const int fr = lane & 15, fk = (lane >> 4) * 8;
    const int rquad = (lane >> 4) * 4, cidx = lane & 15;
    {
      int r = t >> 1, half = t & 1;
      float s = a.speed[m0 + r];
#pragma unroll
      for (int c0 = 0; c0 < 64; c0 += 4) {
        int c = half * 64 + c0;
        float4 wv = *(const float4*)(a.ms_w1 + c);
        float4 bv = *(const float4*)(a.ms_b1 + c);
        hw[r][c + 0] = f2bf(fmaxf(fmaf(s, wv.x, bv.x), 0.f));
        hw[r][c + 1] = f2bf(fmaxf(fmaf(s, wv.y, bv.y), 0.f));
        hw[r][c + 2] = f2bf(fmaxf(fmaf(s, wv.z, bv.z), 0.f));
        hw[r][c + 3] = f2bf(fmaxf(fmaf(s, wv.w, bv.w), 0.f));
      }
    }
    __syncthreads();
    for (int layer = 0; layer < 2; ++layer) {
      const unsigned short* Wt = layer ? a.ms_w3t : a.ms_w2t;
      const float* bb = layer ? a.ms_b3 : a.ms_b2;
      f32x4 acc[4][4];
#pragma unroll
      for (int i = 0; i < 4; ++i)
#pragma unroll
        for (int j = 0; j < 4; ++j)
#pragma unroll
          for (int r = 0; r < 4; ++r) acc[i][j][r] = 0.f;
      for (int k0 = 0; k0 < 128; k0 += 32) {
#pragma unroll
        for (int it = 0; it < 2; ++it) {
          int row = w * 32 + it * 16 + (lane >> 2);
          async16(Wt + (size_t)row * 128 + k0 + (lane & 3) * 8,
                  BsM + (w * 32 + it * 16) * 32);
        }
        __syncthreads();
        bf16x8 af[4], bfv[4];
#pragma unroll
        for (int i = 0; i < 4; ++i)
          af[i] = *(const bf16x8*)(&hw[wm * 64 + i * 16 + fr][k0 + fk]);
#pragma unroll
        for (int j = 0; j < 4; ++j)
          bfv[j] = *(const bf16x8*)(BsM + (wn * 64 + j * 16 + fr) * 32 + fk);
#pragma unroll
        for (int i = 0; i < 4; ++i)
#pragma unroll
          for (int j = 0; j < 4; ++j)
            acc[i][j] = __builtin_amdgcn_mfma_f32_16x16x32_bf16(af[i], bfv[j], acc[i][j], 0, 0, 0);
        __syncthreads();
      }
#pragma unroll
      for (int j = 0; j < 4; ++j) {
        int col = wn * 64 + j * 16 + cidx;
        float bv = bb[col];
#pragma unroll
        for (int i = 0; i < 4; ++i) {
          int row = wm * 64 + i * 16 + rquad;
#pragma unroll
          for (int r = 0; r < 4; ++r) {
            float v = acc[i][j][r] + bv;
            if (layer == 0) v = fmaxf(v, 0.f);
            hw[row + r][col] = f2bf(v);
          }
        }
      }
      __syncthreads();
    }
    {
      int r = t >> 1, half = t & 1;
#pragma unroll
      for (int c8 = 0; c8 < 8; ++c8)
        *(bf16x8*)(a.msout + (size_t)(m0 + r) * 128 + half * 64 + c8 * 8) =
            *(const bf16x8*)(&hw[r][half * 64 + c8 * 8]);
    }
    return;
  }
  if (b >= 128) {            // ---- W_f fuse GEMM
    int idx = b - 128;                 // 0..39
    int mt = idx & 7, nt = idx >> 3;   // M=1024 -> 8 mtiles, N=640 -> 5 ntiles
    gemm128(a.c_w1t, 512, nullptr, 0, 1024, a.wjbf, nullptr, a.wf_t, 640, 0, 512, mt, nt);
    return;
  }
  // ---- place with per-block self-scan
  __shared__ int pf[NCMD][4];
  __shared__ int tot[NCMD];
  int c = t >> 6, lane = t & 63;
  int v[8]; int s = 0;
#pragma unroll
  for (int q = 0; q < 8; ++q) { v[q] = a.wavecnt[c * 512 + lane * 8 + q]; s += v[q]; }
  int p = s;
#pragma unroll
  for (int m = 1; m < 64; m <<= 1) { int o = __shfl_up(p, m, 64); if (lane >= m) p += o; }
  int excl = p - s;
  if (lane == 63) tot[c] = p;
  if (lane == ((4 * b) >> 3)) {
    int base_off = (4 * b) & 7;
    int run = excl;
#pragma unroll
    for (int q = 0; q < 8; ++q) {
      if (q >= base_off && q < base_off + 4) pf[c][q - base_off] = run;
      run += v[q];
    }
  }
  __syncthreads();
  int soffs[NCMD + 1];
  soffs[0] = 0;
#pragma unroll
  for (int e = 0; e < NCMD; ++e) soffs[e + 1] = soffs[e] + tot[e];
  if (b == 0 && t == 0)
    for (int e = 0; e <= NCMD; ++e) a.offs[e] = soffs[e];
  int i = b * 256 + t;
  int mc = a.cmd[i];
  int lwid = t >> 6;
  int rank = 0, base = 0;
#pragma unroll
  for (int cv = 0; cv < NCMD; ++cv) {
    unsigned long long m = __ballot(mc == cv);
    if (mc == cv) {
      rank = __popcll(m & ((1ull << lane) - 1ull));
      base = soffs[cv] + pf[cv][lwid];
    }
  }
  a.perm[base + rank] = i;

  // ---- tile table for k_tail: per-expert 32-row tiles (block 0 only)
  if (b == 0) {
    int toff[NCMD + 1];
    toff[0] = 0;
#pragma unroll
    for (int ee = 0; ee < NCMD; ++ee) toff[ee + 1] = toff[ee] + ((tot[ee] + 31) >> 5);
    if (t == 0) a.ntl[0] = toff[NCMD];
    for (int ti = t; ti < toff[NCMD]; ti += 256) {
      int ee = 0;
      while (ti >= toff[ee + 1]) ++ee;
      a.tile_e[ti] = ee;
      a.tile_r0[ti] = soffs[ee] + (ti - toff[ee]) * 32;
    }
  }
}

// ---- k_tail: fully fused tail, 32-row blocks for occupancy (24 KB LDS,
// ~5-6 blocks/CU). A is reg-staged from feat (f32 -> bf16 in-register) or
// msout (bf16), T14 issue-early/write-late into a double-buffered As chunk
// [32][64] with the proven (cg ^ (row&7)) 16B-slot XOR swizzle on BOTH the
// ds_write and ds_read sides. B is read per-lane direct from global (L2-hot
// weights; col-split waves share no B). Plain __syncthreads only — no inline
// asm (round-1's "memory"-clobbered vmcnt pinned the B loads and exposed
// their latency).
struct TailArgs {
  const float* feat;
  const unsigned short* msout;
  const unsigned short* wf_t;  const float* b_f;
  const unsigned short* sp_w1t; const float* sp_b1;
  const unsigned short* c_w2t; const float* ctrl_b2;
  const unsigned short* sp_w2t; const float* sp_b2;
  const float* ctrl_w3; const float* ctrl_b3;
  const float* sp_w3; const float* sp_b3;
  const int* perm; const int* seg;
  const int* tile_e; const int* tile_r0; const int* ntl;
  float* out;
};
__launch_bounds__(256, 4)
__global__ void k_tail(TailArgs a) {
  extern __shared__ __align__(16) unsigned char dynsm[];
  unsigned short* As = (unsigned short*)dynsm;            // [2 buf][32][64] = 8 KB
  unsigned short* h1 = (unsigned short*)(dynsm + 8192);   // [32][256] swizzled = 16 KB
  float* pscr = (float*)dynsm;                            // [32][4][3] (reuses As)

  const int t = threadIdx.x;
  const int w = t >> 6, lane = t & 63;
  const int fr = lane & 15, fcg = lane >> 4;
  const int rquad = fcg * 4, cidx = fr;
  const int row_s = t >> 3, cg = t & 7;     // staging role: 32 rows x 8 col-octets

  int is_sp, e = 0, NC;
  const unsigned short *W1, *W2;
  const float *b1, *b2;
  int r0, rend;
  if (blockIdx.x < 1024) {
    is_sp = 1; NC = 8;
    W1 = a.sp_w1t; W2 = a.sp_w2t; b1 = a.sp_b1; b2 = a.sp_b2;
    r0 = blockIdx.x * 32; rend = BB;
  } else {
    int ti = blockIdx.x - 1024;
    if (ti >= a.ntl[0]) return;
    is_sp = 0; e = a.tile_e[ti]; NC = 10;
    W1 = a.wf_t + (size_t)e * 256 * 640;
    W2 = a.c_w2t + (size_t)e * 65536;
    b1 = a.b_f + e * 256; b2 = a.ctrl_b2 + e * 256;
    r0 = a.tile_r0[ti]; rend = a.seg[e + 1];
  }
  const int K = is_sp ? 512 : 640;

  // staging sources for this thread's (row, col-octet)
  const float* fsrc; const unsigned short* msrc;
  {
    int rl = r0 + row_s;
    if (rl >= rend) rl = rend - 1;
    int grow = is_sp ? rl : a.perm[rl];
    fsrc = a.feat + (size_t)grow * 512 + cg * 8;
    msrc = a.msout + (size_t)grow * 128 + cg * 8;
  }
  unsigned short* wslot = As + row_s * 64 + ((cg ^ (row_s & 7)) << 3);

  const unsigned short* bp[4];
#pragma unroll
  for (int j = 0; j < 4; ++j)
    bp[j] = W1 + (size_t)(w * 64 + j * 16 + fr) * K + fcg * 8;

  f32x4 acc[2][4];
#pragma unroll
  for (int i = 0; i < 2; ++i)
#pragma unroll
    for (int j = 0; j < 4; ++j)
#pragma unroll
      for (int r = 0; r < 4; ++r) acc[i][j][r] = 0.f;

  // prologue: stage chunk 0 (always f32 region) into buf 0
  {
    float4 fa = *(const float4*)(fsrc);
    float4 fb = *(const float4*)(fsrc + 4);
    *(bf16x8*)(wslot) = pack8(fa, fb);
  }
  __syncthreads();

  for (int c = 0; c < NC; ++c) {
    // 1. issue next-chunk staging loads (latency hides under this chunk's MFMAs)
    float4 fa, fb; bf16x8 mreg;
    const int k0n = (c + 1) * 64;
    const bool pre = (c + 1 < NC);
    if (pre) {
      if (k0n < 512) {
        fa = *(const float4*)(fsrc + k0n);
        fb = *(const float4*)(fsrc + k0n + 4);
      } else {
        mreg = *(const bf16x8*)(msrc + (k0n - 512));
      }
    }
    // 2. compute chunk c
    const unsigned short* cbuf = As + (c & 1) * 2048;
#pragma unroll
    for (int ks = 0; ks < 2; ++ks) {
      const int k0 = c * 64 + ks * 32;
      bf16x8 af[2], bv[4];
#pragma unroll
      for (int i = 0; i < 2; ++i)
        af[i] = *(const bf16x8*)(cbuf + (i * 16 + fr) * 64 +
                                 (((ks * 4 + fcg) ^ (fr & 7)) << 3));
#pragma unroll
      for (int j = 0; j < 4; ++j)
        bv[j] = *(const bf16x8*)(bp[j] + k0);
#pragma unroll
      for (int i = 0; i < 2; ++i)
#pragma unroll
        for (int j = 0; j < 4; ++j)
          acc[i][j] = __builtin_amdgcn_mfma_f32_16x16x32_bf16(af[i], bv[j], acc[i][j], 0, 0, 0);
    }
    __syncthreads();
    // 3. write next chunk into the other buffer
    if (pre) {
      bf16x8 pk;
      if (k0n < 512) pk = pack8(fa, fb);
      else pk = mreg;
      *(bf16x8*)(wslot + ((c + 1) & 1) * 2048) = pk;
    }
    __syncthreads();
  }

  // phase-1 epilogue: relu+bias -> h1 bf16, 16B-slot XOR swizzle
#pragma unroll
  for (int j = 0; j < 4; ++j) {
    const int col = w * 64 + j * 16 + cidx;
    const float bj = b1[col];
    const int c8 = col >> 3, cl = col & 7;
#pragma unroll
    for (int i = 0; i < 2; ++i) {
#pragma unroll
      for (int r = 0; r < 4; ++r) {
        const int row = i * 16 + rquad + r;
        h1[(row << 8) + (((c8 ^ (row & 7)) << 3) | cl)] =
            f2bf(fmaxf(acc[i][j][r] + bj, 0.f));
      }
    }
  }
  __syncthreads();

  // phase 2: h2 = relu(h1 @ W2^T + b2), K=256. No barriers.
  const unsigned short* bp2[4];
#pragma unroll
  for (int j = 0; j < 4; ++j)
    bp2[j] = W2 + (size_t)(w * 64 + j * 16 + fr) * 256 + fcg * 8;

#pragma unroll
  for (int i = 0; i < 2; ++i)
#pragma unroll
    for (int j = 0; j < 4; ++j)
#pragma unroll
      for (int r = 0; r < 4; ++r) acc[i][j][r] = 0.f;

#pragma unroll 2
  for (int k0 = 0; k0 < 256; k0 += 32) {
    bf16x8 af[2], bv[4];
#pragma unroll
    for (int i = 0; i < 2; ++i) {
      const int row = i * 16 + fr;
      const int c8 = (k0 >> 3) + fcg;
      af[i] = *(const bf16x8*)(h1 + (row << 8) + ((c8 ^ (row & 7)) << 3));
    }
#pragma unroll
    for (int j = 0; j < 4; ++j)
      bv[j] = *(const bf16x8*)(bp2[j] + k0);
#pragma unroll
    for (int i = 0; i < 2; ++i)
#pragma unroll
      for (int j = 0; j < 4; ++j)
        acc[i][j] = __builtin_amdgcn_mfma_f32_16x16x32_bf16(af[i], bv[j], acc[i][j], 0, 0, 0);
  }

  // dot with w3 (+bias, relu) and cross-lane reduce over the 16 cidx lanes
  float b2v[4], w30[4], w31[4], w32[4];
#pragma unroll
  for (int j = 0; j < 4; ++j) {
    const int col = w * 64 + j * 16 + cidx;
    b2v[j] = b2[col];
    if (is_sp) {
      w30[j] = a.sp_w3[col]; w31[j] = 0.f; w32[j] = 0.f;
    } else {
      const float* wp = a.ctrl_w3 + (size_t)e * 768 + col * 3;
      w30[j] = wp[0]; w31[j] = wp[1]; w32[j] = wp[2];
    }
  }
#pragma unroll
  for (int i = 0; i < 2; ++i) {
#pragma unroll
    for (int r = 0; r < 4; ++r) {
      float s0 = 0.f, s1 = 0.f, s2 = 0.f;
#pragma unroll
      for (int j = 0; j < 4; ++j) {
        const float v = fmaxf(acc[i][j][r] + b2v[j], 0.f);
        s0 = fmaf(v, w30[j], s0);
        if (!is_sp) { s1 = fmaf(v, w31[j], s1); s2 = fmaf(v, w32[j], s2); }
      }
#pragma unroll
      for (int m = 1; m <= 8; m <<= 1) {
        s0 += __shfl_xor(s0, m, 64);
        if (!is_sp) { s1 += __shfl_xor(s1, m, 64); s2 += __shfl_xor(s2, m, 64); }
      }
      if (cidx == 0) {
        const int row = i * 16 + rquad + r;
        pscr[(row * 4 + w) * 3 + 0] = s0;
        if (!is_sp) {
          pscr[(row * 4 + w) * 3 + 1] = s1;
          pscr[(row * 4 + w) * 3 + 2] = s2;
        }
      }
    }
  }
  __syncthreads();

  if (is_sp) {
    if (t < 32) {
      float s = pscr[t * 12] + pscr[t * 12 + 3] + pscr[t * 12 + 6] + pscr[t * 12 + 9]
              + a.sp_b3[0];
      a.out[r0 + t] = s;                                  // v_p (no activation)
    }
  } else {
    if (t < 96) {
      const int row = t / 3, o = t - row * 3;
      const int rl = r0 + row;
      if (rl < rend) {
        float s = pscr[row * 12 + o] + pscr[row * 12 + 3 + o] +
                  pscr[row * 12 + 6 + o] + pscr[row * 12 + 9 + o] +
                  a.ctrl_b3[e * 3 + o];
        const int orig = a.perm[rl];
        if (o == 0)      a.out[BB + orig]     = 1.f / (1.f + __expf(-s));  // throttle
        else if (o == 2) a.out[2 * BB + orig] = 1.f / (1.f + __expf(-s));  // brake
        else             a.out[3 * BB + orig] = tanhf(s);                  // steering
      }
    }
  }
}

static inline size_t align256(size_t x) { return (x + 255) & ~(size_t)255; }

extern "C" void kernel_launch(void* const* d_in, const int* in_sizes, int n_in,
                              void* d_out, int out_size, void* d_ws, size_t ws_size,
                              hipStream_t stream) {
  const float* feat   = (const float*)d_in[0];
  const float* speed  = (const float*)d_in[1];
  const int*   command= (const int*)d_in[2];
  const float* ms_w1  = (const float*)d_in[3];
  const float* ms_b1  = (const float*)d_in[4];
  const float* ms_w2  = (const float*)d_in[5];
  const float* ms_b2  = (const float*)d_in[6];
  const float* ms_w3  = (const float*)d_in[7];
  const float* ms_b3  = (const float*)d_in[8];
  const float* sp_w1  = (const float*)d_in[9];
  const float* sp_b1  = (const float*)d_in[10];
  const float* sp_w2  = (const float*)d_in[11];
  const float* sp_b2  = (const float*)d_in[12];
  const float* sp_w3  = (const float*)d_in[13];
  const float* sp_b3  = (const float*)d_in[14];
  const float* join_w = (const float*)d_in[15];
  const float* join_b = (const float*)d_in[16];
  const float* ctrl_w1= (const float*)d_in[17];
  const float* ctrl_b1= (const float*)d_in[18];
  const float* ctrl_w2= (const float*)d_in[19];
  const float* ctrl_b2= (const float*)d_in[20];
  const float* ctrl_w3= (const float*)d_in[21];
  const float* ctrl_b3= (const float*)d_in[22];
  float* out = (float*)d_out;

  char* ws = (char*)d_ws;
  size_t off = 0;
  auto alloc = [&](size_t bytes) -> char* { char* p = ws + off; off = align256(off + bytes); return p; };

  unsigned short* msout  = (unsigned short*)alloc((size_t)BB * 128 * 2);
  unsigned short* wtp    = (unsigned short*)alloc(1998848ull * 2);
  int* perm    = (int*)alloc((size_t)BB * 4);
  int* cnt     = (int*)alloc(64);        // offs[5] at cnt+4
  int* wavecnt = (int*)alloc(4 * 512 * 4);
  float* b_f   = (float*)alloc(4 * 256 * 4);
  int* tile_e  = (int*)alloc(1056 * 4);
  int* tile_r0 = (int*)alloc(1056 * 4);
  int* ntl     = (int*)alloc(64);

  unsigned short* sp_w1t = wtp;                 // [256][512]
  unsigned short* sp_w2t = wtp + 131072;        // [256][256]
  unsigned short* ms_w2t = wtp + 196608;        // [128][128]
  unsigned short* ms_w3t = wtp + 212992;        // [128][128]
  unsigned short* c_w1t  = wtp + 229376;        // [4][256][512]
  unsigned short* c_w2t  = wtp + 753664;        // [4][256][256]
  unsigned short* wjbf   = wtp + 1015808;       // [640][512] straight bf16
  unsigned short* wf_t   = wtp + 1343488;       // [4][256][640] fused W_f^T

  PrepArgs P;
  P.s[0] = { sp_w1, sp_w1t, 512, 256, 512 };
  P.s[1] = { sp_w2, sp_w2t, 256, 256, 256 };
  P.s[2] = { ms_w2, ms_w2t, 128, 128, 128 };
  P.s[3] = { ms_w3, ms_w3t, 128, 128, 128 };
  for (int e = 0; e < 4; ++e) P.s[4 + e] = { ctrl_w1 + (size_t)e * 512 * 256, c_w1t + (size_t)e * 131072, 512, 256, 512 };
  for (int e = 0; e < 4; ++e) P.s[8 + e] = { ctrl_w2 + (size_t)e * 256 * 256, c_w2t + (size_t)e * 65536, 256, 256, 256 };
  P.start[0] = 0;
  for (int i = 0; i < 12; ++i)
    P.start[i + 1] = P.start[i] + (P.s[i].K >> 5) * (P.s[i].N >> 5);
  P.join_w = join_w; P.wjbf = wjbf;
  P.cmd = command; P.wavecnt = wavecnt;
  P.join_b = join_b; P.ctrl_w1 = ctrl_w1; P.ctrl_b1 = ctrl_b1; P.b_f = b_f;
  int prep_blocks = 320 + P.start[12] + 128 + 4;

  k_prep<<<prep_blocks, 256, 0, stream>>>(P);

  MidArgs Mi;
  Mi.cmd = command; Mi.wavecnt = wavecnt; Mi.perm = perm; Mi.offs = cnt + 4;
  Mi.c_w1t = c_w1t; Mi.wjbf = wjbf; Mi.wf_t = wf_t;
  Mi.speed = speed;
  Mi.ms_w1 = ms_w1; Mi.ms_b1 = ms_b1;
  Mi.ms_w2t = ms_w2t; Mi.ms_b2 = ms_b2;
  Mi.ms_w3t = ms_w3t; Mi.ms_b3 = ms_b3;
  Mi.msout = msout;
  Mi.tile_e = tile_e; Mi.tile_r0 = tile_r0; Mi.ntl = ntl;
  k_mid<<<168 + 256, 256, 128 * 136 * 2 + 128 * 32 * 2, stream>>>(Mi);

  TailArgs T;
  T.feat = feat; T.msout = msout;
  T.wf_t = wf_t; T.b_f = b_f;
  T.sp_w1t = sp_w1t; T.sp_b1 = sp_b1;
  T.c_w2t = c_w2t; T.ctrl_b2 = ctrl_b2;
  T.sp_w2t = sp_w2t; T.sp_b2 = sp_b2;
  T.ctrl_w3 = ctrl_w3; T.ctrl_b3 = ctrl_b3;
  T.sp_w3 = sp_w3; T.sp_b3 = sp_b3;
  T.perm = perm; T.seg = cnt + 4;
  T.tile_e = tile_e; T.tile_r0 = tile_r0; T.ntl = ntl;
  T.out = out;
  // 1024 sp tiles + up to 1028 padded ctrl tiles; 24 KB dyn LDS
  k_tail<<<dim3(1024 + 1028), 256, 24576, stream>>>(T);
}

// Round 3
// 230.003 us; speedup vs baseline: 1.1642x; 1.1642x over previous
//
#include <hip/hip_runtime.h>
#include <hip/hip_bf16.h>
#include <stdint.h>
#include <math.h>

#define BB 32768
#define FEAT 512
#define SPD_H 128
#define CTRL_H 256
#define NCMD 4

typedef __attribute__((ext_vector_type(8))) short bf16x8;
typedef __attribute__((ext_vector_type(4))) float f32x4;

__device__ __forceinline__ unsigned short f2bf(float f) {
  union { float f; uint32_t u; } v; v.f = f;
  uint32_t u = v.u;
  return (unsigned short)((u + 0x7fffu + ((u >> 16) & 1u)) >> 16); // RNE
}

__device__ __forceinline__ bf16x8 pack8(float4 a, float4 b) {
  bf16x8 r;
  r[0] = (short)f2bf(a.x); r[1] = (short)f2bf(a.y);
  r[2] = (short)f2bf(a.z); r[3] = (short)f2bf(a.w);
  r[4] = (short)f2bf(b.x); r[5] = (short)f2bf(b.y);
  r[6] = (short)f2bf(b.z); r[7] = (short)f2bf(b.w);
  return r;
}

// async global->LDS, 16B per lane; LDS dest = wave-uniform base + lane*16
__device__ __forceinline__ void async16(const unsigned short* g, unsigned short* l) {
  __builtin_amdgcn_global_load_lds(
      (const __attribute__((address_space(1))) unsigned int*)g,
      (__attribute__((address_space(3))) unsigned int*)l, 16, 0, 0);
}

// ---------------- shared 128x128 bf16 MFMA GEMM tile (device fn) --------------
// Used only by k_mid's W_f fuse GEMM. 16 KB of DYNAMIC LDS.
__device__ __forceinline__ void gemm128(
    const unsigned short* __restrict__ A, int lda,
    const int* __restrict__ perm, int m_start, int m_cnt,
    const unsigned short* __restrict__ W, const float* __restrict__ bi,
    unsigned short* __restrict__ C, int ldc, int relu, int K, int mt, int nt) {
  extern __shared__ __align__(16) unsigned char dynsm[];
  unsigned short* As = (unsigned short*)dynsm;
  unsigned short* Bs = As + 128 * 32;

  const int m0 = mt * 128;
  if (m0 >= m_cnt) return;
  const int n0 = nt * 128;
  const int t = threadIdx.x;
  const int w = t >> 6, lane = t & 63;
  const int wm = w & 1, wn = w >> 1;

  f32x4 acc[4][4];
#pragma unroll
  for (int i = 0; i < 4; ++i)
#pragma unroll
    for (int j = 0; j < 4; ++j)
#pragma unroll
      for (int r = 0; r < 4; ++r) acc[i][j][r] = 0.f;

  const int fr = lane & 15;
  const int fk = (lane >> 4) * 8;

  const unsigned short* agp[2]; const unsigned short* bgp[2];
  unsigned short* al[2]; unsigned short* bl[2];
#pragma unroll
  for (int it = 0; it < 2; ++it) {
    int row = w * 32 + it * 16 + (lane >> 2);
    int seg8 = (lane & 3) * 8;
    int rl = m0 + row;
    if (rl >= m_cnt) rl = m_cnt - 1;
    int grow = perm ? perm[m_start + rl] : (m_start + rl);
    agp[it] = A + (size_t)grow * lda + seg8;
    bgp[it] = W + (size_t)(n0 + row) * K + seg8;
    al[it] = As + (w * 32 + it * 16) * 32;
    bl[it] = Bs + (w * 32 + it * 16) * 32;
  }

  for (int k0 = 0; k0 < K; k0 += 32) {
#pragma unroll
    for (int it = 0; it < 2; ++it) {
      async16(agp[it] + k0, al[it]);
      async16(bgp[it] + k0, bl[it]);
    }
    __syncthreads();
    bf16x8 af[4], bfv[4];
#pragma unroll
    for (int i = 0; i < 4; ++i)
      af[i] = *(const bf16x8*)(As + (wm * 64 + i * 16 + fr) * 32 + fk);
#pragma unroll
    for (int j = 0; j < 4; ++j)
      bfv[j] = *(const bf16x8*)(Bs + (wn * 64 + j * 16 + fr) * 32 + fk);
#pragma unroll
    for (int i = 0; i < 4; ++i)
#pragma unroll
      for (int j = 0; j < 4; ++j)
        acc[i][j] = __builtin_amdgcn_mfma_f32_16x16x32_bf16(af[i], bfv[j], acc[i][j], 0, 0, 0);
    __syncthreads();
  }

  const int rquad = (lane >> 4) * 4;
  const int cidx = lane & 15;

  float bv[4];
#pragma unroll
  for (int j = 0; j < 4; ++j) bv[j] = bi ? bi[n0 + wn * 64 + j * 16 + cidx] : 0.f;

  unsigned short (*bscr)[136] = (unsigned short(*)[136])dynsm;
#pragma unroll
  for (int c = 0; c < 4; ++c) {
    if (wm == (c >> 1)) {
#pragma unroll
      for (int j = 0; j < 4; ++j) {
#pragma unroll
        for (int ii = 0; ii < 2; ++ii) {
          int i = 2 * (c & 1) + ii;
          int lr = ii * 16 + rquad;
#pragma unroll
          for (int r = 0; r < 4; ++r) {
            float v = acc[i][j][r] + bv[j];
            if (relu) v = fmaxf(v, 0.f);
            bscr[lr + r][wn * 64 + j * 16 + cidx] = f2bf(v);
          }
        }
      }
    }
    __syncthreads();
#pragma unroll
    for (int q = 0; q < 2; ++q) {
      int sg = t + 256 * q;
      int lr = sg >> 4, cs = (sg & 15) * 8;
      int grow = m0 + c * 32 + lr;
      if (grow < m_cnt)
        *(bf16x8*)(C + (size_t)(m_start + grow) * ldc + (n0 + cs)) =
            *(const bf16x8*)(&bscr[lr][cs]);
    }
    __syncthreads();
  }
}

// --- prep: weight converts/transposes + count + b_f ---------------------------
struct WSeg { const float* src; unsigned short* dst; int K; int N; int ldd; };
struct PrepArgs {
  WSeg s[12];
  int start[13];
  const float* join_w; unsigned short* wjbf;
  const int* cmd; int* wavecnt;
  const float* join_b; const float* ctrl_w1; const float* ctrl_b1; float* b_f;
};
__launch_bounds__(256)
__global__ void k_prep(PrepArgs a) {
  int bx = blockIdx.x, t = threadIdx.x;
  if (bx < 320) {            // ---- join_w straight convert
    int idx = bx * 256 + t;
    float4 f = *(const float4*)(a.join_w + (size_t)idx * 4);
    ushort4 o;
    o.x = f2bf(f.x); o.y = f2bf(f.y); o.z = f2bf(f.z); o.w = f2bf(f.w);
    *(ushort4*)(a.wjbf + (size_t)idx * 4) = o;
    return;
  }
  int rel = bx - 320;
  if (rel < a.start[12]) {   // ---- 32x32 transpose tiles
    __shared__ float tb[32][33];
    int si = 0;
    while (rel >= a.start[si + 1]) ++si;
    WSeg sg = a.s[si];
    int tile = rel - a.start[si];
    int tkx = sg.K >> 5;
    int tn = tile / tkx;
    int tk = tile - tn * tkx;
    int k0 = tk * 32, n0 = tn * 32;
    int tx = t & 31, ty = t >> 5;
#pragma unroll
    for (int j = 0; j < 4; ++j)
      tb[ty + j * 8][tx] = sg.src[(size_t)(k0 + ty + j * 8) * sg.N + n0 + tx];
    __syncthreads();
#pragma unroll
    for (int j = 0; j < 4; ++j)
      sg.dst[(size_t)(n0 + ty + j * 8) * sg.ldd + k0 + tx] = f2bf(tb[tx][ty + j * 8]);
    return;
  }
  rel -= a.start[12];
  if (rel < 128) {           // ---- command count (ballot histogram)
    int i = rel * 256 + t;
    int c = a.cmd[i];
    int wid = i >> 6;
    int lane = t & 63;
#pragma unroll
    for (int cv = 0; cv < NCMD; ++cv) {
      unsigned long long m = __ballot(c == cv);
      if (lane == 0) a.wavecnt[cv * 512 + wid] = __popcll(m);
    }
    return;
  }
  // ---- b_f[e][n] = join_b . ctrl_w1[e][:,n] + ctrl_b1[e][n]
  int e = rel - 128;
  float s0 = a.ctrl_b1[e * 256 + t], s1 = 0.f, s2 = 0.f, s3 = 0.f;
  const float* w = a.ctrl_w1 + (size_t)e * 512 * 256 + t;
#pragma unroll 4
  for (int m = 0; m < 512; m += 4) {
    s0 = fmaf(a.join_b[m + 0], w[(size_t)(m + 0) * 256], s0);
    s1 = fmaf(a.join_b[m + 1], w[(size_t)(m + 1) * 256], s1);
    s2 = fmaf(a.join_b[m + 2], w[(size_t)(m + 2) * 256], s2);
    s3 = fmaf(a.join_b[m + 3], w[(size_t)(m + 3) * 256], s3);
  }
  a.b_f[e * 256 + t] = (s0 + s1) + (s2 + s3);
}

// -- k_mid: place (0..127) + W_f fuse GEMM (128..167) + ms module (168..423) ---
struct MidArgs {
  const int* cmd; const int* wavecnt; int* perm; int* offs;
  const unsigned short* c_w1t; const unsigned short* wjbf; unsigned short* wf_t;
  const float* speed;
  const float* ms_w1; const float* ms_b1;
  const unsigned short* ms_w2t; const float* ms_b2;
  const unsigned short* ms_w3t; const float* ms_b3;
  unsigned short* msout;
  int* tile_e; int* tile_r0; int* ntl;
};
__launch_bounds__(256)
__global__ void k_mid(MidArgs a) {
  int b = blockIdx.x, t = threadIdx.x;
  if (b >= 168) {            // ---- measured-speed module (MFMA, LDS-resident)
    extern __shared__ __align__(16) unsigned char dynsm[];
    unsigned short (*hw)[136] = (unsigned short(*)[136])dynsm;
    unsigned short* BsM = (unsigned short*)(dynsm + 128 * 136 * 2);
    const int m0 = (b - 168) * 128;
    const int w = t >> 6, lane = t & 63;
    const int wm = w & 1, wn = w >> 1;
    const int fr = lane & 15, fk = (lane >> 4) * 8;
    const int rquad = (lane >> 4) * 4, cidx = lane & 15;
    {
      int r = t >> 1, half = t & 1;
      float s = a.speed[m0 + r];
#pragma unroll
      for (int c0 = 0; c0 < 64; c0 += 4) {
        int c = half * 64 + c0;
        float4 wv = *(const float4*)(a.ms_w1 + c);
        float4 bv = *(const float4*)(a.ms_b1 + c);
        hw[r][c + 0] = f2bf(fmaxf(fmaf(s, wv.x, bv.x), 0.f));
        hw[r][c + 1] = f2bf(fmaxf(fmaf(s, wv.y, bv.y), 0.f));
        hw[r][c + 2] = f2bf(fmaxf(fmaf(s, wv.z, bv.z), 0.f));
        hw[r][c + 3] = f2bf(fmaxf(fmaf(s, wv.w, bv.w), 0.f));
      }
    }
    __syncthreads();
    for (int layer = 0; layer < 2; ++layer) {
      const unsigned short* Wt = layer ? a.ms_w3t : a.ms_w2t;
      const float* bb = layer ? a.ms_b3 : a.ms_b2;
      f32x4 acc[4][4];
#pragma unroll
      for (int i = 0; i < 4; ++i)
#pragma unroll
        for (int j = 0; j < 4; ++j)
#pragma unroll
          for (int r = 0; r < 4; ++r) acc[i][j][r] = 0.f;
      for (int k0 = 0; k0 < 128; k0 += 32) {
#pragma unroll
        for (int it = 0; it < 2; ++it) {
          int row = w * 32 + it * 16 + (lane >> 2);
          async16(Wt + (size_t)row * 128 + k0 + (lane & 3) * 8,
                  BsM + (w * 32 + it * 16) * 32);
        }
        __syncthreads();
        bf16x8 af[4], bfv[4];
#pragma unroll
        for (int i = 0; i < 4; ++i)
          af[i] = *(const bf16x8*)(&hw[wm * 64 + i * 16 + fr][k0 + fk]);
#pragma unroll
        for (int j = 0; j < 4; ++j)
          bfv[j] = *(const bf16x8*)(BsM + (wn * 64 + j * 16 + fr) * 32 + fk);
#pragma unroll
        for (int i = 0; i < 4; ++i)
#pragma unroll
          for (int j = 0; j < 4; ++j)
            acc[i][j] = __builtin_amdgcn_mfma_f32_16x16x32_bf16(af[i], bfv[j], acc[i][j], 0, 0, 0);
        __syncthreads();
      }
#pragma unroll
      for (int j = 0; j < 4; ++j) {
        int col = wn * 64 + j * 16 + cidx;
        float bv = bb[col];
#pragma unroll
        for (int i = 0; i < 4; ++i) {
          int row = wm * 64 + i * 16 + rquad;
#pragma unroll
          for (int r = 0; r < 4; ++r) {
            float v = acc[i][j][r] + bv;
            if (layer == 0) v = fmaxf(v, 0.f);
            hw[row + r][col] = f2bf(v);
          }
        }
      }
      __syncthreads();
    }
    {
      int r = t >> 1, half = t & 1;
#pragma unroll
      for (int c8 = 0; c8 < 8; ++c8)
        *(bf16x8*)(a.msout + (size_t)(m0 + r) * 128 + half * 64 + c8 * 8) =
            *(const bf16x8*)(&hw[r][half * 64 + c8 * 8]);
    }
    return;
  }
  if (b >= 128) {            // ---- W_f fuse GEMM
    int idx = b - 128;                 // 0..39
    int mt = idx & 7, nt = idx >> 3;   // M=1024 -> 8 mtiles, N=640 -> 5 ntiles
    gemm128(a.c_w1t, 512, nullptr, 0, 1024, a.wjbf, nullptr, a.wf_t, 640, 0, 512, mt, nt);
    return;
  }
  // ---- place with per-block self-scan
  __shared__ int pf[NCMD][4];
  __shared__ int tot[NCMD];
  int c = t >> 6, lane = t & 63;
  int v[8]; int s = 0;
#pragma unroll
  for (int q = 0; q < 8; ++q) { v[q] = a.wavecnt[c * 512 + lane * 8 + q]; s += v[q]; }
  int p = s;
#pragma unroll
  for (int m = 1; m < 64; m <<= 1) { int o = __shfl_up(p, m, 64); if (lane >= m) p += o; }
  int excl = p - s;
  if (lane == 63) tot[c] = p;
  if (lane == ((4 * b) >> 3)) {
    int base_off = (4 * b) & 7;
    int run = excl;
#pragma unroll
    for (int q = 0; q < 8; ++q) {
      if (q >= base_off && q < base_off + 4) pf[c][q - base_off] = run;
      run += v[q];
    }
  }
  __syncthreads();
  int soffs[NCMD + 1];
  soffs[0] = 0;
#pragma unroll
  for (int e = 0; e < NCMD; ++e) soffs[e + 1] = soffs[e] + tot[e];
  if (b == 0 && t == 0)
    for (int e = 0; e <= NCMD; ++e) a.offs[e] = soffs[e];
  int i = b * 256 + t;
  int mc = a.cmd[i];
  int lwid = t >> 6;
  int rank = 0, base = 0;
#pragma unroll
  for (int cv = 0; cv < NCMD; ++cv) {
    unsigned long long m = __ballot(mc == cv);
    if (mc == cv) {
      rank = __popcll(m & ((1ull << lane) - 1ull));
      base = soffs[cv] + pf[cv][lwid];
    }
  }
  a.perm[base + rank] = i;

  // ---- tile table for k_tail: per-expert 64-row tiles (block 0 only)
  if (b == 0) {
    int toff[NCMD + 1];
    toff[0] = 0;
#pragma unroll
    for (int ee = 0; ee < NCMD; ++ee) toff[ee + 1] = toff[ee] + ((tot[ee] + 63) >> 6);
    if (t == 0) a.ntl[0] = toff[NCMD];
    for (int ti = t; ti < toff[NCMD]; ti += 256) {
      int ee = 0;
      while (ti >= toff[ee + 1]) ++ee;
      a.tile_e[ti] = ee;
      a.tile_r0[ti] = soffs[ee] + (ti - toff[ee]) * 64;
    }
  }
}

// ---- k_tail: fused tail, 64-row tiles (weight re-read traffic halves vs 32).
// 4 waves as 1M x 4N: wave w owns output cols w*64..w*64+63, all 64 rows
// (acc[4][4]; 32 MFMA per 64-col chunk per wave vs 8 B-loads + 8 ds_reads).
// ONE __syncthreads per chunk: [ds_write next chunk (regs staged last iter)]
// -> [issue global loads for chunk c+2] -> [ds_read cur + B direct + MFMA]
// -> barrier. Every global load crosses exactly one barrier-drain ~1 full
// chunk after issue; f32->bf16 pack deferred to the ds_write (consume point)
// so the loads get real latency cover. As uses a 16B-octet XOR swizzle
// (oct ^ (row&7)) on write and read; h1 keeps the proven R2 swizzle.
struct TailArgs {
  const float* feat;
  const unsigned short* msout;
  const unsigned short* wf_t;  const float* b_f;
  const unsigned short* sp_w1t; const float* sp_b1;
  const unsigned short* c_w2t; const float* ctrl_b2;
  const unsigned short* sp_w2t; const float* sp_b2;
  const float* ctrl_w3; const float* ctrl_b3;
  const float* sp_w3; const float* sp_b3;
  const int* perm; const int* seg;
  const int* tile_e; const int* tile_r0; const int* ntl;
  float* out;
};
__launch_bounds__(256, 3)
__global__ void k_tail(TailArgs a) {
  extern __shared__ __align__(16) unsigned char dynsm[];
  unsigned short* As = (unsigned short*)dynsm;            // [2][64][64] = 16 KB
  unsigned short* h1 = (unsigned short*)(dynsm + 16384);  // [64][256] swizzled = 32 KB
  float* pscr = (float*)dynsm;                            // [64][4][3] (reuses As)

  const int t = threadIdx.x;
  const int w = t >> 6, lane = t & 63;
  const int fr = lane & 15, fcg = lane >> 4;
  const int rquad = fcg * 4, cidx = fr;
  const int row_s = t >> 2, sl = t & 3;   // staging: 64 rows x 4 slots (2 octets each)

  int is_sp, e = 0, NC;
  const unsigned short *W1, *W2;
  const float *b1, *b2;
  int r0, rend;
  if (blockIdx.x < 512) {
    is_sp = 1; NC = 8;
    W1 = a.sp_w1t; W2 = a.sp_w2t; b1 = a.sp_b1; b2 = a.sp_b2;
    r0 = blockIdx.x * 64; rend = BB;
  } else {
    int ti = blockIdx.x - 512;
    if (ti >= a.ntl[0]) return;
    is_sp = 0; e = a.tile_e[ti]; NC = 10;
    W1 = a.wf_t + (size_t)e * 256 * 640;
    W2 = a.c_w2t + (size_t)e * 65536;
    b1 = a.b_f + e * 256; b2 = a.ctrl_b2 + e * 256;
    r0 = a.tile_r0[ti]; rend = a.seg[e + 1];
  }
  const int K = is_sp ? 512 : 640;

  // staging sources for this thread's (row, 16-f32 slice)
  const float* fsrc; const unsigned short* msrc;
  {
    int rl = r0 + row_s;
    if (rl >= rend) rl = rend - 1;
    int grow = is_sp ? rl : a.perm[rl];
    fsrc = a.feat + (size_t)grow * 512 + sl * 16;
    msrc = a.msout + (size_t)grow * 128 + sl * 16;
  }
  const int xr = row_s & 7;
  unsigned short* wp0 = As + row_s * 64 + (((2 * sl) ^ xr) << 3);
  unsigned short* wp1 = As + row_s * 64 + (((2 * sl + 1) ^ xr) << 3);

  const unsigned short* bp[4];
#pragma unroll
  for (int j = 0; j < 4; ++j)
    bp[j] = W1 + (size_t)(w * 64 + j * 16 + fr) * K + fcg * 8;

  f32x4 acc[4][4];
#pragma unroll
  for (int i = 0; i < 4; ++i)
#pragma unroll
    for (int j = 0; j < 4; ++j)
#pragma unroll
      for (int r = 0; r < 4; ++r) acc[i][j][r] = 0.f;

  // pipeline registers: staged data for one chunk (raw; packed at write time)
  float4 g0, g1, g2, g3; bf16x8 mv0, mv1;

#define LOADA(cc)                                                        \
  do {                                                                   \
    if ((cc) < 8) {                                                      \
      g0 = *(const float4*)(fsrc + (cc) * 64 + 0);                       \
      g1 = *(const float4*)(fsrc + (cc) * 64 + 4);                       \
      g2 = *(const float4*)(fsrc + (cc) * 64 + 8);                       \
      g3 = *(const float4*)(fsrc + (cc) * 64 + 12);                      \
    } else {                                                             \
      mv0 = *(const bf16x8*)(msrc + ((cc) - 8) * 64 + 0);                \
      mv1 = *(const bf16x8*)(msrc + ((cc) - 8) * 64 + 8);                \
    }                                                                    \
  } while (0)

#define WRITEA(cc, bufb)                                                 \
  do {                                                                   \
    bf16x8 s0_, s1_;                                                     \
    if ((cc) < 8) { s0_ = pack8(g0, g1); s1_ = pack8(g2, g3); }          \
    else { s0_ = mv0; s1_ = mv1; }                                       \
    *(bf16x8*)(wp0 + (bufb)) = s0_;                                      \
    *(bf16x8*)(wp1 + (bufb)) = s1_;                                      \
  } while (0)

  // prologue: chunk 0 -> buf0; chunk 1 staged in regs
  LOADA(0);
  WRITEA(0, 0);
  LOADA(1);
  __syncthreads();

  for (int c = 0; c < NC; ++c) {
    const int cr = (c & 1) * 4096;
    if (c + 1 < NC) WRITEA(c + 1, ((c + 1) & 1) * 4096);
    if (c + 2 < NC) LOADA(c + 2);
#pragma unroll
    for (int ks = 0; ks < 2; ++ks) {
      const int k0 = c * 64 + ks * 32;
      bf16x8 af[4], bv[4];
#pragma unroll
      for (int i = 0; i < 4; ++i)
        af[i] = *(const bf16x8*)(As + cr + (i * 16 + fr) * 64 +
                                 (((ks * 4 + fcg) ^ (fr & 7)) << 3));
#pragma unroll
      for (int j = 0; j < 4; ++j)
        bv[j] = *(const bf16x8*)(bp[j] + k0);
#pragma unroll
      for (int i = 0; i < 4; ++i)
#pragma unroll
        for (int j = 0; j < 4; ++j)
          acc[i][j] = __builtin_amdgcn_mfma_f32_16x16x32_bf16(af[i], bv[j], acc[i][j], 0, 0, 0);
    }
    __syncthreads();
  }
#undef LOADA
#undef WRITEA

  // phase-1 epilogue: relu+bias -> h1 bf16, 16B-slot XOR swizzle
#pragma unroll
  for (int j = 0; j < 4; ++j) {
    const int col = w * 64 + j * 16 + cidx;
    const float bj = b1[col];
    const int c8 = col >> 3, cl = col & 7;
#pragma unroll
    for (int i = 0; i < 4; ++i) {
#pragma unroll
      for (int r = 0; r < 4; ++r) {
        const int row = i * 16 + rquad + r;
        h1[(row << 8) + (((c8 ^ (row & 7)) << 3) | cl)] =
            f2bf(fmaxf(acc[i][j][r] + bj, 0.f));
      }
    }
  }
  __syncthreads();

  // phase 2: h2 = relu(h1 @ W2^T + b2), K=256. No barriers.
  const unsigned short* bp2[4];
#pragma unroll
  for (int j = 0; j < 4; ++j)
    bp2[j] = W2 + (size_t)(w * 64 + j * 16 + fr) * 256 + fcg * 8;

#pragma unroll
  for (int i = 0; i < 4; ++i)
#pragma unroll
    for (int j = 0; j < 4; ++j)
#pragma unroll
      for (int r = 0; r < 4; ++r) acc[i][j][r] = 0.f;

#pragma unroll 2
  for (int k0 = 0; k0 < 256; k0 += 32) {
    bf16x8 af[4], bv[4];
#pragma unroll
    for (int i = 0; i < 4; ++i) {
      const int row = i * 16 + fr;
      const int c8 = (k0 >> 3) + fcg;
      af[i] = *(const bf16x8*)(h1 + (row << 8) + ((c8 ^ (row & 7)) << 3));
    }
#pragma unroll
    for (int j = 0; j < 4; ++j)
      bv[j] = *(const bf16x8*)(bp2[j] + k0);
#pragma unroll
    for (int i = 0; i < 4; ++i)
#pragma unroll
      for (int j = 0; j < 4; ++j)
        acc[i][j] = __builtin_amdgcn_mfma_f32_16x16x32_bf16(af[i], bv[j], acc[i][j], 0, 0, 0);
  }

  // dot with w3 (+bias, relu) and cross-lane reduce over the 16 cidx lanes
  float b2v[4], w30[4], w31[4], w32[4];
#pragma unroll
  for (int j = 0; j < 4; ++j) {
    const int col = w * 64 + j * 16 + cidx;
    b2v[j] = b2[col];
    if (is_sp) {
      w30[j] = a.sp_w3[col]; w31[j] = 0.f; w32[j] = 0.f;
    } else {
      const float* wp = a.ctrl_w3 + (size_t)e * 768 + col * 3;
      w30[j] = wp[0]; w31[j] = wp[1]; w32[j] = wp[2];
    }
  }
#pragma unroll
  for (int i = 0; i < 4; ++i) {
#pragma unroll
    for (int r = 0; r < 4; ++r) {
      float s0 = 0.f, s1 = 0.f, s2 = 0.f;
#pragma unroll
      for (int j = 0; j < 4; ++j) {
        const float v = fmaxf(acc[i][j][r] + b2v[j], 0.f);
        s0 = fmaf(v, w30[j], s0);
        if (!is_sp) { s1 = fmaf(v, w31[j], s1); s2 = fmaf(v, w32[j], s2); }
      }
#pragma unroll
      for (int m = 1; m <= 8; m <<= 1) {
        s0 += __shfl_xor(s0, m, 64);
        if (!is_sp) { s1 += __shfl_xor(s1, m, 64); s2 += __shfl_xor(s2, m, 64); }
      }
      if (cidx == 0) {
        const int row = i * 16 + rquad + r;
        pscr[(row * 4 + w) * 3 + 0] = s0;
        if (!is_sp) {
          pscr[(row * 4 + w) * 3 + 1] = s1;
          pscr[(row * 4 + w) * 3 + 2] = s2;
        }
      }
    }
  }
  __syncthreads();

  if (is_sp) {
    if (t < 64) {
      float s = pscr[t * 12] + pscr[t * 12 + 3] + pscr[t * 12 + 6] + pscr[t * 12 + 9]
              + a.sp_b3[0];
      a.out[r0 + t] = s;                                  // v_p (no activation)
    }
  } else {
    if (t < 192) {
      const int row = t / 3, o = t - row * 3;
      const int rl = r0 + row;
      if (rl < rend) {
        float s = pscr[row * 12 + o] + pscr[row * 12 + 3 + o] +
                  pscr[row * 12 + 6 + o] + pscr[row * 12 + 9 + o] +
                  a.ctrl_b3[e * 3 + o];
        const int orig = a.perm[rl];
        if (o == 0)      a.out[BB + orig]     = 1.f / (1.f + __expf(-s));  // throttle
        else if (o == 2) a.out[2 * BB + orig] = 1.f / (1.f + __expf(-s));  // brake
        else             a.out[3 * BB + orig] = tanhf(s);                  // steering
      }
    }
  }
}

static inline size_t align256(size_t x) { return (x + 255) & ~(size_t)255; }

extern "C" void kernel_launch(void* const* d_in, const int* in_sizes, int n_in,
                              void* d_out, int out_size, void* d_ws, size_t ws_size,
                              hipStream_t stream) {
  const float* feat   = (const float*)d_in[0];
  const float* speed  = (const float*)d_in[1];
  const int*   command= (const int*)d_in[2];
  const float* ms_w1  = (const float*)d_in[3];
  const float* ms_b1  = (const float*)d_in[4];
  const float* ms_w2  = (const float*)d_in[5];
  const float* ms_b2  = (const float*)d_in[6];
  const float* ms_w3  = (const float*)d_in[7];
  const float* ms_b3  = (const float*)d_in[8];
  const float* sp_w1  = (const float*)d_in[9];
  const float* sp_b1  = (const float*)d_in[10];
  const float* sp_w2  = (const float*)d_in[11];
  const float* sp_b2  = (const float*)d_in[12];
  const float* sp_w3  = (const float*)d_in[13];
  const float* sp_b3  = (const float*)d_in[14];
  const float* join_w = (const float*)d_in[15];
  const float* join_b = (const float*)d_in[16];
  const float* ctrl_w1= (const float*)d_in[17];
  const float* ctrl_b1= (const float*)d_in[18];
  const float* ctrl_w2= (const float*)d_in[19];
  const float* ctrl_b2= (const float*)d_in[20];
  const float* ctrl_w3= (const float*)d_in[21];
  const float* ctrl_b3= (const float*)d_in[22];
  float* out = (float*)d_out;

  char* ws = (char*)d_ws;
  size_t off = 0;
  auto alloc = [&](size_t bytes) -> char* { char* p = ws + off; off = align256(off + bytes); return p; };

  unsigned short* msout  = (unsigned short*)alloc((size_t)BB * 128 * 2);
  unsigned short* wtp    = (unsigned short*)alloc(1998848ull * 2);
  int* perm    = (int*)alloc((size_t)BB * 4);
  int* cnt     = (int*)alloc(64);        // offs[5] at cnt+4
  int* wavecnt = (int*)alloc(4 * 512 * 4);
  float* b_f   = (float*)alloc(4 * 256 * 4);
  int* tile_e  = (int*)alloc(1056 * 4);
  int* tile_r0 = (int*)alloc(1056 * 4);
  int* ntl     = (int*)alloc(64);

  unsigned short* sp_w1t = wtp;                 // [256][512]
  unsigned short* sp_w2t = wtp + 131072;        // [256][256]
  unsigned short* ms_w2t = wtp + 196608;        // [128][128]
  unsigned short* ms_w3t = wtp + 212992;        // [128][128]
  unsigned short* c_w1t  = wtp + 229376;        // [4][256][512]
  unsigned short* c_w2t  = wtp + 753664;        // [4][256][256]
  unsigned short* wjbf   = wtp + 1015808;       // [640][512] straight bf16
  unsigned short* wf_t   = wtp + 1343488;       // [4][256][640] fused W_f^T

  PrepArgs P;
  P.s[0] = { sp_w1, sp_w1t, 512, 256, 512 };
  P.s[1] = { sp_w2, sp_w2t, 256, 256, 256 };
  P.s[2] = { ms_w2, ms_w2t, 128, 128, 128 };
  P.s[3] = { ms_w3, ms_w3t, 128, 128, 128 };
  for (int e = 0; e < 4; ++e) P.s[4 + e] = { ctrl_w1 + (size_t)e * 512 * 256, c_w1t + (size_t)e * 131072, 512, 256, 512 };
  for (int e = 0; e < 4; ++e) P.s[8 + e] = { ctrl_w2 + (size_t)e * 256 * 256, c_w2t + (size_t)e * 65536, 256, 256, 256 };
  P.start[0] = 0;
  for (int i = 0; i < 12; ++i)
    P.start[i + 1] = P.start[i] + (P.s[i].K >> 5) * (P.s[i].N >> 5);
  P.join_w = join_w; P.wjbf = wjbf;
  P.cmd = command; P.wavecnt = wavecnt;
  P.join_b = join_b; P.ctrl_w1 = ctrl_w1; P.ctrl_b1 = ctrl_b1; P.b_f = b_f;
  int prep_blocks = 320 + P.start[12] + 128 + 4;

  k_prep<<<prep_blocks, 256, 0, stream>>>(P);

  MidArgs Mi;
  Mi.cmd = command; Mi.wavecnt = wavecnt; Mi.perm = perm; Mi.offs = cnt + 4;
  Mi.c_w1t = c_w1t; Mi.wjbf = wjbf; Mi.wf_t = wf_t;
  Mi.speed = speed;
  Mi.ms_w1 = ms_w1; Mi.ms_b1 = ms_b1;
  Mi.ms_w2t = ms_w2t; Mi.ms_b2 = ms_b2;
  Mi.ms_w3t = ms_w3t; Mi.ms_b3 = ms_b3;
  Mi.msout = msout;
  Mi.tile_e = tile_e; Mi.tile_r0 = tile_r0; Mi.ntl = ntl;
  k_mid<<<168 + 256, 256, 128 * 136 * 2 + 128 * 32 * 2, stream>>>(Mi);

  TailArgs T;
  T.feat = feat; T.msout = msout;
  T.wf_t = wf_t; T.b_f = b_f;
  T.sp_w1t = sp_w1t; T.sp_b1 = sp_b1;
  T.c_w2t = c_w2t; T.ctrl_b2 = ctrl_b2;
  T.sp_w2t = sp_w2t; T.sp_b2 = sp_b2;
  T.ctrl_w3 = ctrl_w3; T.ctrl_b3 = ctrl_b3;
  T.sp_w3 = sp_w3; T.sp_b3 = sp_b3;
  T.perm = perm; T.seg = cnt + 4;
  T.tile_e = tile_e; T.tile_r0 = tile_r0; T.ntl = ntl;
  T.out = out;
  // 512 sp tiles + up to 516 padded ctrl tiles; 48 KB dyn LDS -> 3 blocks/CU
  k_tail<<<dim3(512 + 516), 256, 49152, stream>>>(T);
}